// Round 7
// baseline (785.236 us; speedup 1.0000x reference)
//
#include <hip/hip_runtime.h>

#define BLK 64
#define XSTR 168      // LDS activation row stride in u16 (16B-aligned rows, 4-way-max banks)

typedef unsigned short u16;
typedef __attribute__((ext_vector_type(8)))  short bf16x8;
typedef __attribute__((ext_vector_type(8)))  unsigned short u16x8;
typedef __attribute__((ext_vector_type(4)))  unsigned short u16x4;
typedef __attribute__((ext_vector_type(4)))  float f32x4;
typedef __attribute__((ext_vector_type(16))) float f32x16;

struct KArgs { const void* p[29]; void* out; };

__device__ __forceinline__ float b2f(u16 u) { return __uint_as_float(((unsigned)u) << 16); }
__device__ __forceinline__ u16 f2b(float f) {
    unsigned x = __float_as_uint(f);
    return (u16)((x + 0x7FFFu + ((x >> 16) & 1u)) >> 16);   // RNE
}

// ---- epilogue chunk descriptors (verified; chunk20 = action_emb[col 32])
__device__ __constant__ unsigned char EP_KIND[31] = {
    0,0,0,0,0,0,0,0,0,0,0,0, 1,1,1,1, 0,0,0, 1, 0,0,0,0,0, 1,1,1,1,1,1 };
__device__ __constant__ unsigned char EP_P1[31] = {
    40,19,38,38,38,38,38,19,19,19,19,19, 0,2,3,5, 19,26,52, 1, 26,19,52,45,19, 4,4,4,4,4,4 };
__device__ __constant__ unsigned char EP_P2[31] = {
    18,20,22,23,24,25,26,27,28,29,30,31, 40,41,42,43, 35,36,37, 39, 32,33,34,19,38, 44,45,46,47,48,49 };

// ---- natural-k fragment-ordered weight arena. 9 layers (hb L1 back to NT=5).
// Fragment f (global index), lane l, elem j at arena[f*512 + l*8 + j].
// For layer L with frag base F0: fi=f-F0, kk=fi/NT, t=fi%NT,
//   value = W[(kk*16 + (l>>5)*8 + j) * N + (32t + (l&31))]   (0 if col >= N)
__device__ __constant__ int P3_K16[9]  = {4,5,4,5,4,5,9,9,4};
__device__ __constant__ int P3_NT[9]   = {2,3,2,3,2,3,5,2,2};
__device__ __constant__ int P3_N[9]    = {64,80,64,80,64,80,144,64,64};
__device__ __constant__ int P3_F0[9]   = {0,8,23,31,46,54,69,114,132};
__device__ __constant__ int P3_BOFF[9] = {0,64,160,224,320,384,480,640,704};
__device__ __constant__ int P3_WIDX[9] = {3,9,5,11,7,13,15,17,19};
#define NFRAG 140
#define BIAS_BYTE_OFF 155648          // arena = 140*512 u16 = 143360 B; 16B aligned

__device__ __forceinline__ bool probe_f32(const void* st) {
    const u16* p = (const u16*)st;
    unsigned o = 0;
    #pragma unroll
    for (int j = 1; j <= 16; j++) o |= p[100 * j];
    return o == 0;                    // f32 layout: low16 of integral floats are 0
}

__global__ void poker_prep(KArgs a, u16* arena, float* biasar)
{
    const bool F32 = probe_f32(a.p[0]);
    const int L = blockIdx.x;
    const int K16 = P3_K16[L], NT = P3_NT[L], N = P3_N[L];
    const void* W = a.p[P3_WIDX[L]];
    const void* b = a.p[P3_WIDX[L] + 1];
    u16* wt = arena + P3_F0[L] * 512;
    const int total = K16 * NT * 512;
    for (int e = threadIdx.x; e < total; e += blockDim.x) {
        int f = e >> 9, w = e & 511;
        int l = w >> 3, j = w & 7;
        int kk = f / NT, t = f - kk * NT;
        int n = 32 * t + (l & 31);
        int k = kk * 16 + ((l >> 5) << 3) + j;
        float v = 0.f;
        if (n < N)
            v = F32 ? ((const float*)W)[k * N + n] : b2f(((const u16*)W)[k * N + n]);
        wt[e] = f2b(v);
    }
    const int BN = NT * 32;
    if ((int)threadIdx.x < BN) {
        float v = ((int)threadIdx.x < N)
            ? (F32 ? ((const float*)b)[threadIdx.x] : b2f(((const u16*)b)[threadIdx.x]))
            : 0.f;
        biasar[P3_BOFF[L] + threadIdx.x] = v;
    }
}

// One layer, SHARED code (__noinline__, 4 instantiations for 9 call sites).
// Operand-swapped MFMA (R0-proven layout):
//   A = weight fragment (m = n_out), B = x rows from LDS (n = row = lane&31)
//   D: lane (n32+32h), acc[t][4g+j] = out-feature 32t + 8g + 4h + j  -> natural-order LDS write
template<int NT, int K16>
__device__ __noinline__ void layer_f(
    const u16* __restrict__ arena, int f0, const float* __restrict__ sb,
    const u16* __restrict__ src, u16* __restrict__ dst, int act, int lane)
{
    const int h = lane >> 5, n32 = lane & 31;
    const u16* xp = src + n32 * XSTR + h * 8;
    const u16* wp = arena + f0 * 512 + lane * 8;
    f32x16 acc[NT] = {};
    #pragma unroll
    for (int kk = 0; kk < K16; kk++) {
        bf16x8 xf = *(const bf16x8*)(xp + kk * 16);
        #pragma unroll
        for (int t = 0; t < NT; t++) {
            bf16x8 wf = *(const bf16x8*)(wp + (kk * NT + t) * 512);
            acc[t] = __builtin_amdgcn_mfma_f32_32x32x16_bf16(wf, xf, acc[t], 0, 0, 0);
        }
    }
    const float leak = act ? 0.01f : 1.0f;     // fmax(v, v) == v for non-NaN: branchless
    u16* dp = dst + n32 * XSTR + 4 * h;
    #pragma unroll
    for (int t = 0; t < NT; t++) {
        #pragma unroll
        for (int g = 0; g < 4; g++) {
            f32x4 bv = *(const f32x4*)(sb + t * 32 + 8 * g + 4 * h);
            u16x4 pk;
            #pragma unroll
            for (int j = 0; j < 4; j++) {
                float v = acc[t][4 * g + j] + bv[j];
                v = fmaxf(v, leak * v);
                pk[j] = f2b(v);
            }
            *(u16x4*)(dp + t * 32 + 8 * g) = pk;
        }
    }
}

template<bool F32>
__device__ void body(
    const KArgs& a, const u16* __restrict__ arena,
    u16* s_emb, float* s_scalW, float* s_scalB, float* sb,
    float* ss, u16* sX, u16* sY, int lane, long row0)
{
    // ---- dense state staging: 32 rows into LDS f32 (no barrier: single wave per block)
    if constexpr (F32) {
        const char* gb = (const char*)a.p[0] + row0 * 200;
        for (int i = 0; i < 7; i++) {
            int fo = i * 1024 + lane * 16;
            if (fo < 6400)
                *(f32x4*)((char*)ss + fo) = *(const f32x4*)(gb + fo);
        }
    } else {
        const char* gb = (const char*)a.p[0] + row0 * 100;
        for (int i = 0; i < 7; i++) {
            int uo = i * 512 + lane * 8;
            if (uo < 3200) {
                u16x4 w = *(const u16x4*)(gb + uo);
                f32x4 v = { b2f(w[0]), b2f(w[1]), b2f(w[2]), b2f(w[3]) };
                *(f32x4*)((char*)ss + uo * 2) = v;
            }
        }
    }

    // ---- card gather from LDS state -> s_X rows (natural order): [hand 4x16 | board 5x16]
    for (int u = lane; u < 288; u += 64) {
        int r = u / 9, cd = u - 9 * r;
        int rkc, stc, db;
        if (cd < 4) { rkc = 2 * cd;     stc = 2 * cd + 1;  db = r * XSTR + cd * 16; }
        else { int c2 = cd - 4; rkc = 8 + 2 * c2; stc = 9 + 2 * c2; db = r * XSTR + 64 + c2 * 16; }
        int st = (int)(ss[r * 50 + stc] + 0.5f);
        int rk = (int)(ss[r * 50 + rkc] + 0.5f);
        *(u16x8*)&sX[db]     = *(const u16x8*)&s_emb[st * 8];
        *(u16x8*)&sX[db + 8] = *(const u16x8*)&s_emb[(5 + rk) * 8];
    }

    // ---- 9 layers via 4 shared code bodies (frag stream 0,8,23,31,46,54,69,114,132)
    layer_f<2,4>(arena,   0, sb + 0,   sX,      sY,      1, lane);   // hand L1
    layer_f<3,5>(arena,   8, sb + 64,  sX + 64, sY + 64, 1, lane);   // board L1
    layer_f<2,4>(arena,  23, sb + 160, sY,      sX,      1, lane);   // hand L2
    layer_f<3,5>(arena,  31, sb + 224, sY + 64, sX + 64, 1, lane);   // board L2
    layer_f<2,4>(arena,  46, sb + 320, sX,      sY,      0, lane);   // hand L3
    layer_f<3,5>(arena,  54, sb + 384, sX + 64, sY + 64, 0, lane);   // board L3
    layer_f<5,9>(arena,  69, sb + 480, sY,      sX,      1, lane);   // hb L1 (writes 160 cols)
    layer_f<2,9>(arena, 114, sb + 640, sX,      sY,      1, lane);   // hb L2
    layer_f<2,4>(arena, 132, sb + 704, sY,      sX,      0, lane);   // hb L3 -> sX cols 0..63

    // ---- epilogue: 312 cols = 39 chunks x 8 (looped, compact code)
    if constexpr (F32) {
        float* obase = (float*)a.out + row0 * 312;
        const int hf = lane & 1, ql = lane >> 1;
        for (int i = 0; i < 39; i++) {
            int q = 32 * i + ql;
            int r2 = q / 39, c = q - 39 * r2;
            f32x4 ov;
            if (c < 8) {
                u16x4 w = *(const u16x4*)&sX[r2 * XSTR + c * 8 + hf * 4];
                ov[0] = b2f(w[0]); ov[1] = b2f(w[1]); ov[2] = b2f(w[2]); ov[3] = b2f(w[3]);
            } else {
                int e = c - 8;
                int col = EP_P2[e], p1 = EP_P1[e];
                float sv = ss[r2 * 50 + col];
                if (EP_KIND[e] == 0) {
                    int idx = (int)(sv + 0.5f);
                    u16x4 w = *(const u16x4*)&s_emb[(p1 + idx) * 8 + hf * 4];
                    ov[0] = b2f(w[0]); ov[1] = b2f(w[1]); ov[2] = b2f(w[2]); ov[3] = b2f(w[3]);
                } else {
                    #pragma unroll
                    for (int j = 0; j < 4; j++)
                        ov[j] = fmaf(sv, s_scalW[p1 * 8 + hf * 4 + j], s_scalB[p1 * 8 + hf * 4 + j]);
                }
            }
            *(f32x4*)(obase + i * 256 + lane * 4) = ov;    // dense 1KB wave store
        }
    } else {
        for (int i = 0; i < 20; i++) {
            int u = lane + 64 * i;
            if (u < 1248) {
                int r2 = u / 39, c = u - 39 * r2;
                float v[8];
                if (c < 8) {
                    u16x8 w = *(const u16x8*)&sX[r2 * XSTR + c * 8];
                    #pragma unroll
                    for (int j = 0; j < 8; j++) v[j] = b2f(w[j]);
                } else {
                    int e = c - 8;
                    int col = EP_P2[e], p1 = EP_P1[e];
                    float sv = ss[r2 * 50 + col];
                    if (EP_KIND[e] == 0) {
                        int idx = (int)(sv + 0.5f);
                        u16x8 w = *(const u16x8*)&s_emb[(p1 + idx) * 8];
                        #pragma unroll
                        for (int j = 0; j < 8; j++) v[j] = b2f(w[j]);
                    } else {
                        #pragma unroll
                        for (int j = 0; j < 8; j++)
                            v[j] = fmaf(sv, s_scalW[p1 * 8 + j], s_scalB[p1 * 8 + j]);
                    }
                }
                u16x8 w;
                #pragma unroll
                for (int j = 0; j < 8; j++) w[j] = f2b(v[j]);
                *(u16x8*)&((u16*)a.out)[(row0 + r2) * 312 + c * 8] = w;
            }
        }
    }
}

__global__ __launch_bounds__(BLK, 2) void poker_main(
    KArgs a, const u16* __restrict__ arena, const float* __restrict__ biasar)
{
    __shared__ alignas(16) u16   s_X[32 * XSTR];
    __shared__ alignas(16) u16   s_Y[32 * XSTR];
    __shared__ alignas(16) float s_state[32 * 50];
    __shared__ alignas(16) float s_bias[768];
    __shared__ alignas(16) u16   s_emb[54 * 8];
    __shared__ alignas(16) float s_scalW[48];
    __shared__ alignas(16) float s_scalB[48];

    const int lane = threadIdx.x;
    const long row0 = (long)blockIdx.x * 32;
    const bool isf32 = probe_f32(a.p[0]);

    // ---- staging of tiny tables (single wave: no barrier anywhere in the kernel)
    {
        const void* srcs[8] = { a.p[1], a.p[2], a.p[21], a.p[22], a.p[23], a.p[24], a.p[25], a.p[26] };
        const int  cnt[8]   = { 5, 14, 7, 12, 2, 5, 7, 2 };
        int base = 0;
        for (int t = 0; t < 8; t++) {
            int n = cnt[t] * 8;
            for (int i = lane; i < n; i += BLK)
                s_emb[base + i] = isf32 ? f2b(((const float*)srcs[t])[i]) : ((const u16*)srcs[t])[i];
            base += n;
        }
        if (lane < 48) {
            s_scalW[lane] = isf32 ? ((const float*)a.p[27])[lane] : b2f(((const u16*)a.p[27])[lane]);
            s_scalB[lane] = isf32 ? ((const float*)a.p[28])[lane] : b2f(((const u16*)a.p[28])[lane]);
        }
        for (int i = lane; i < 192; i += BLK)
            ((f32x4*)s_bias)[i] = ((const f32x4*)biasar)[i];
    }
    // same-wave LDS write->read ordering guaranteed by in-order DS + lgkmcnt

    if (isf32) body<true >(a, arena, s_emb, s_scalW, s_scalB, s_bias, s_state, s_X, s_Y, lane, row0);
    else       body<false>(a, arena, s_emb, s_scalW, s_scalB, s_bias, s_state, s_X, s_Y, lane, row0);
}

extern "C" void kernel_launch(void* const* d_in, const int* in_sizes, int n_in,
                              void* d_out, int out_size, void* d_ws, size_t ws_size,
                              hipStream_t stream) {
    KArgs args;
    for (int i = 0; i < 29; i++) args.p[i] = d_in[i];
    args.out = d_out;
    u16*   arena  = (u16*)d_ws;
    float* biasar = (float*)((char*)d_ws + BIAS_BYTE_OFF);
    int rows = in_sizes[0] / 50;          // 262144
    int blocks = rows / 32;               // 8192

    poker_prep<<<dim3(9), dim3(256), 0, stream>>>(args, arena, biasar);
    poker_main<<<dim3(blocks), dim3(BLK), 0, stream>>>(args, arena, biasar);
}

// Round 8
// 523.613 us; speedup vs baseline: 1.4996x; 1.4996x over previous
//
#include <hip/hip_runtime.h>

#define BLK 256          // 4 waves, 128 rows per block
#define NFRAG 140
#define NCHUNK 9         // 9 chunks x 16 frags (arena padded to 144 frags)
#define CHUNK_U16 8192   // 16 frags * 512 u16 = 16KB

typedef unsigned short u16;
typedef __attribute__((ext_vector_type(8)))  short bf16x8;
typedef __attribute__((ext_vector_type(8)))  unsigned short u16x8;
typedef __attribute__((ext_vector_type(4)))  unsigned short u16x4;
typedef __attribute__((ext_vector_type(4)))  float f32x4;
typedef __attribute__((ext_vector_type(16))) float f32x16;
typedef __attribute__((ext_vector_type(4)))  unsigned int u32x4;

struct KArgs { const void* p[29]; void* out; };

__device__ __forceinline__ float b2f(u16 u) { return __uint_as_float(((unsigned)u) << 16); }
__device__ __forceinline__ u16 f2b(float f) {
    unsigned x = __float_as_uint(f);
    return (u16)((x + 0x7FFFu + ((x >> 16) & 1u)) >> 16);   // RNE
}

// ---- epilogue chunk descriptors (verified; chunk20 = action_emb[col 32])
__device__ __constant__ unsigned char EP_KIND[31] = {
    0,0,0,0,0,0,0,0,0,0,0,0, 1,1,1,1, 0,0,0, 1, 0,0,0,0,0, 1,1,1,1,1,1 };
__device__ __constant__ unsigned char EP_P1[31] = {
    40,19,38,38,38,38,38,19,19,19,19,19, 0,2,3,5, 19,26,52, 1, 26,19,52,45,19, 4,4,4,4,4,4 };
__device__ __constant__ unsigned char EP_P2[31] = {
    18,20,22,23,24,25,26,27,28,29,30,31, 40,41,42,43, 35,36,37, 39, 32,33,34,19,38, 44,45,46,47,48,49 };

// ---- fragment-ordered weight arena (R3/R5-verified). 10 logical layers (hb L1 split).
// Fragment f, lane l, elem j at arena[f*512 + l*8 + j];
// value = W[perm(k)*N + NOFF + 32t + (l&31)], k = kk*16 + (l>>5)*8 + j, f = F0 + kk*NT + t.
// perm = swap k bits 2<->3 for layers consuming D-packed activations (all but the first two).
__device__ __constant__ int P2_K[10]    = {64,80,64,80,64,80,144,144,144,64};
__device__ __constant__ int P2_NT[10]   = {2,3,2,3,2,3,3,2,2,2};
__device__ __constant__ int P2_N[10]    = {64,80,64,80,64,80,144,144,64,64};
__device__ __constant__ int P2_NOFF[10] = {0,0,0,0,0,0,0,96,0,0};
__device__ __constant__ int P2_WOFF[10] = {0,4096,11776,15872,23552,27648,35328,49152,58368,67584};
__device__ __constant__ int P2_BOFF[10] = {0,64,160,224,320,384,480,576,640,704};
__device__ __constant__ int P2_WIDX[10] = {3,9,5,11,7,13,15,15,17,19};
__device__ __constant__ int P2_PERM[10] = {0,0,1,1,1,1,1,1,1,1};
#define BIAS_BYTE_OFF 155648          // arena = 144*512 u16 = 147456 B < this; 16B aligned

__device__ __forceinline__ bool probe_f32(const void* st) {
    const u16* p = (const u16*)st;
    unsigned o = 0;
    #pragma unroll
    for (int j = 1; j <= 16; j++) o |= p[100 * j];
    return o == 0;                    // f32 layout: low16 of integral floats are 0
}

__global__ void poker_prep(KArgs a, u16* arena, float* biasar)
{
    const int L = blockIdx.x;
    if (L == 10) {                     // zero pad frags 140..143 (staged, never consumed)
        for (int e = threadIdx.x; e < 4 * 512; e += blockDim.x) arena[140 * 512 + e] = 0;
        return;
    }
    const bool F32 = probe_f32(a.p[0]);
    const int K = P2_K[L], NT = P2_NT[L], N = P2_N[L], NO = P2_NOFF[L], PM = P2_PERM[L];
    const void* W = a.p[P2_WIDX[L]];
    const void* b = a.p[P2_WIDX[L] + 1];
    u16* wt = arena + P2_WOFF[L];
    const int total = NT * K * 32;    // u16 elems
    for (int e = threadIdx.x; e < total; e += blockDim.x) {
        int f = e >> 3, j = e & 7;
        int l = f & 63, fi = f >> 6;
        int kk = fi / NT, t = fi - kk * NT;
        int n = NO + 32 * t + (l & 31);
        int k = kk * 16 + ((l >> 5) << 3) + j;
        int ks = PM ? ((k & ~12) | ((k & 4) << 1) | ((k & 8) >> 1)) : k;  // swap bits 2<->3
        float v = 0.f;
        if (n < N)
            v = F32 ? ((const float*)W)[ks * N + n] : b2f(((const u16*)W)[ks * N + n]);
        wt[e] = f2b(v);
    }
    const int BN = NT * 32;
    if ((int)threadIdx.x < BN) {
        int n = NO + threadIdx.x;
        float v = (n < N)
            ? (F32 ? ((const float*)b)[n] : b2f(((const u16*)b)[n]))
            : 0.f;
        biasar[P2_BOFF[L] + threadIdx.x] = v;
    }
}

// stage one 16KB chunk: 4 waves x 4 fragments, each gll = 1KB (lane-linear dest)
__device__ __forceinline__ void stage_chunk(
    const u16* __restrict__ arena, u16* __restrict__ sw, int c, int wave, int lane)
{
    #pragma unroll
    for (int i = 0; i < 4; i++) {
        int fs = wave * 4 + i;                     // frag-in-chunk 0..15
        const u16* g = arena + (c * 16 + fs) * 512 + lane * 8;
        u16* l = sw + (c % 3) * CHUNK_U16 + fs * 512;
        __builtin_amdgcn_global_load_lds(
            (const __attribute__((address_space(1))) unsigned int*)g,
            (__attribute__((address_space(3))) unsigned int*)l, 16, 0, 0);
    }
}

// consume fragments [FI0,FI1) of the layer starting at frag F0 (NT accumulators)
template<int F0, int NT, int FI0, int FI1>
__device__ __forceinline__ void seg(
    const u16* __restrict__ sw, f32x16* acc, const bf16x8* __restrict__ x, int lane)
{
    #pragma unroll
    for (int fi = FI0; fi < FI1; fi++) {
        const int f = F0 + fi;
        const int kk = fi / NT, t = fi - kk * NT;
        const u16* p = sw + ((f >> 4) % 3) * CHUNK_U16 + (f & 15) * 512 + lane * 8;
        acc[t] = __builtin_amdgcn_mfma_f32_32x32x16_bf16(*(const bf16x8*)p, x[kk], acc[t], 0, 0, 0);
    }
}

// layer epilogue: bias + leaky-relu + RNE pack into D-pack order (R5-verified, bit-identical)
template<int NT, int NCO, bool ACT>
__device__ __forceinline__ void epi(const f32x16* acc, const float* __restrict__ sb,
                                    bf16x8* __restrict__ y, int h)
{
    #pragma unroll
    for (int t = 0; t < NT; t++) {
        #pragma unroll
        for (int s = 0; s < 2; s++) {
            if (2 * t + s < NCO) {
                unsigned w[4];
                #pragma unroll
                for (int gg = 0; gg < 2; gg++) {
                    const int G = 2 * s + gg;
                    f32x4 bv = *(const f32x4*)(sb + t * 32 + 8 * G + 4 * h);
                    float v0 = acc[t][4 * G + 0] + bv[0];
                    float v1 = acc[t][4 * G + 1] + bv[1];
                    float v2 = acc[t][4 * G + 2] + bv[2];
                    float v3 = acc[t][4 * G + 3] + bv[3];
                    if (ACT) {
                        v0 = fmaxf(v0, 0.01f * v0); v1 = fmaxf(v1, 0.01f * v1);
                        v2 = fmaxf(v2, 0.01f * v2); v3 = fmaxf(v3, 0.01f * v3);
                    }
                    w[2 * gg + 0] = (unsigned)f2b(v0) | ((unsigned)f2b(v1) << 16);
                    w[2 * gg + 1] = (unsigned)f2b(v2) | ((unsigned)f2b(v3) << 16);
                }
                u32x4 fw = { w[0], w[1], w[2], w[3] };
                y[2 * t + s] = __builtin_bit_cast(bf16x8, fw);
            }
        }
    }
}

template<bool F32>
__device__ void body(
    const KArgs& a, const u16* __restrict__ arena,
    u16* s_emb, float* s_scalW, float* s_scalB, float* sb,
    float* ss /*wave's 32x50 state*/, u16* sw /*3-slot weight staging*/,
    int lane, int wave, long row0)
{
    const int rbase = wave * 32;
    const int h = lane >> 5, r = lane & 31;

    // ---- dense state staging (per wave): 32 rows flat copy into LDS f32
    if constexpr (F32) {
        const char* gb = (const char*)a.p[0] + (row0 + rbase) * 200;
        #pragma unroll
        for (int i = 0; i < 7; i++) {
            int fo = i * 1024 + lane * 16;
            if (fo < 6400)
                *(f32x4*)((char*)ss + fo) = *(const f32x4*)(gb + fo);
        }
    } else {
        const char* gb = (const char*)a.p[0] + (row0 + rbase) * 100;
        #pragma unroll
        for (int i = 0; i < 7; i++) {
            int uo = i * 512 + lane * 8;
            if (uo < 3200) {
                u16x4 w = *(const u16x4*)(gb + uo);
                f32x4 v = { b2f(w[0]), b2f(w[1]), b2f(w[2]), b2f(w[3]) };
                *(f32x4*)((char*)ss + uo * 2) = v;
            }
        }
    }

    // ---- weight prologue: chunks 0,1 in flight; barrier drains them (and all staging)
    stage_chunk(arena, sw, 0, wave, lane);
    stage_chunk(arena, sw, 1, wave, lane);
    __syncthreads();   // compiler emits s_waitcnt vmcnt(0) lgkmcnt(0) before s_barrier

    // ---- card gather from LDS state -> register fragments (natural k order)
    const float* srow = ss + r * 50;
    bf16x8 xh[4], xb[5];
    #pragma unroll
    for (int c = 0; c < 9; c++) {
        float fv = srow[2 * c + 1 - h];           // h=0: suit col, h=1: rank col
        int idx = (int)(fv + 0.5f);
        bf16x8 ev = *(const bf16x8*)&s_emb[(h ? 5 + idx : idx) * 8];
        if (c < 4) xh[c] = ev; else xb[c - 4] = ev;
    }

    // ---- chunked layer pipeline. Iter c: stage c+2 (overlaps compute), compute chunk c,
    //      barrier (drains stage, syncs slot rotation). Slots: read c%3, write (c+2)%3.
    bf16x8 h1[4], b1[5], h2[4], b2v[5], hb[9], c1[9], c2[4], c3[4];
    {   // chunk 0: L0 full (frags 0-7) + L1 fi 0-7
        f32x16 aL0[2] = {}; f32x16 aL1[3] = {};
        stage_chunk(arena, sw, 2, wave, lane);
        seg<  0, 2, 0,  8>(sw, aL0, xh, lane);  epi<2, 4, true >(aL0, sb + 0, h1, h);
        seg<  8, 3, 0,  8>(sw, aL1, xb, lane);
        __syncthreads();
        // chunk 1: L1 fi 8-14 (epi) + L2 full + L3 fi 0
        f32x16 aL2[2] = {}; f32x16 aL3[3] = {};
        stage_chunk(arena, sw, 3, wave, lane);
        seg<  8, 3, 8, 15>(sw, aL1, xb, lane);  epi<3, 5, true >(aL1, sb + 64, b1, h);
        seg< 23, 2, 0,  8>(sw, aL2, h1, lane);  epi<2, 4, true >(aL2, sb + 160, h2, h);
        seg< 31, 3, 0,  1>(sw, aL3, b1, lane);
        __syncthreads();
        // chunk 2: L3 fi 1-14 (epi) + L4 fi 0-1
        f32x16 aL4[2] = {};
        stage_chunk(arena, sw, 4, wave, lane);
        seg< 31, 3, 1, 15>(sw, aL3, b1, lane);  epi<3, 5, true >(aL3, sb + 224, b2v, h);
        seg< 46, 2, 0,  2>(sw, aL4, h2, lane);
        __syncthreads();
        // chunk 3: L4 fi 2-7 (epi) + L5 fi 0-9
        f32x16 aL5[3] = {};
        stage_chunk(arena, sw, 5, wave, lane);
        seg< 46, 2, 2,  8>(sw, aL4, h2, lane);  epi<2, 4, false>(aL4, sb + 320, hb, h);
        seg< 54, 3, 0, 10>(sw, aL5, b2v, lane);
        __syncthreads();
        // chunk 4: L5 fi 10-14 (epi) + L6a fi 0-10
        f32x16 a6a[3] = {};
        stage_chunk(arena, sw, 6, wave, lane);
        seg< 54, 3, 10, 15>(sw, aL5, b2v, lane); epi<3, 5, false>(aL5, sb + 384, hb + 4, h);
        seg< 69, 3, 0, 11>(sw, a6a, hb, lane);
        __syncthreads();
        // chunk 5: L6a fi 11-26 (epi)
        stage_chunk(arena, sw, 7, wave, lane);
        seg< 69, 3, 11, 27>(sw, a6a, hb, lane); epi<3, 6, true >(a6a, sb + 480, c1, h);
        __syncthreads();
        // chunk 6: L6b fi 0-15
        f32x16 a6b[2] = {};
        stage_chunk(arena, sw, 8, wave, lane);
        seg< 96, 2, 0, 16>(sw, a6b, hb, lane);
        __syncthreads();
        // chunk 7: L6b fi 16-17 (epi) + L8 fi 0-13
        f32x16 aL8[2] = {};
        seg< 96, 2, 16, 18>(sw, a6b, hb, lane); epi<2, 3, true >(a6b, sb + 576, c1 + 6, h);
        seg<114, 2, 0, 14>(sw, aL8, c1, lane);
        __syncthreads();
        // chunk 8: L8 fi 14-17 (epi) + L9 full (epi)
        f32x16 aL9[2] = {};
        seg<114, 2, 14, 18>(sw, aL8, c1, lane); epi<2, 4, true >(aL8, sb + 640, c2, h);
        seg<132, 2, 0,  8>(sw, aL9, c2, lane);  epi<2, 4, false>(aL9, sb + 704, c3, h);
    }

    // ---- staging slots are dead (all waves past the chunk-7 barrier; chunk-8 reads are
    //      wave-local at offset >= 16384 u16); reuse slot0/1 region for HB de-swizzle.
    u16* hbp = sw + wave * 2304;               // 4 waves x 2304 u16 = 9216 < 16384
    #pragma unroll
    for (int c = 0; c < 4; c++) {
        u16x4 lo = { (u16)c3[c][0], (u16)c3[c][1], (u16)c3[c][2], (u16)c3[c][3] };
        u16x4 hi = { (u16)c3[c][4], (u16)c3[c][5], (u16)c3[c][6], (u16)c3[c][7] };
        *(u16x4*)&hbp[r * 72 + c * 16 + 4 * h]     = lo;
        *(u16x4*)&hbp[r * 72 + c * 16 + 8 + 4 * h] = hi;
    }

    // ---- final epilogue (per wave, 32 rows)
    if constexpr (F32) {
        float* obase = (float*)a.out + (row0 + rbase) * 312;
        const int hf = lane & 1, ql = lane >> 1;
        #pragma unroll 13
        for (int i = 0; i < 39; i++) {
            int q = 32 * i + ql;
            int r2 = q / 39, c = q - 39 * r2;
            f32x4 ov;
            if (c < 8) {
                u16x4 w = *(const u16x4*)&hbp[r2 * 72 + c * 8 + hf * 4];
                ov[0] = b2f(w[0]); ov[1] = b2f(w[1]); ov[2] = b2f(w[2]); ov[3] = b2f(w[3]);
            } else {
                int e = c - 8;
                int col = EP_P2[e], p1 = EP_P1[e];
                float sv = ss[r2 * 50 + col];
                if (EP_KIND[e] == 0) {
                    int idx = (int)(sv + 0.5f);
                    u16x4 w = *(const u16x4*)&s_emb[(p1 + idx) * 8 + hf * 4];
                    ov[0] = b2f(w[0]); ov[1] = b2f(w[1]); ov[2] = b2f(w[2]); ov[3] = b2f(w[3]);
                } else {
                    #pragma unroll
                    for (int j = 0; j < 4; j++)
                        ov[j] = fmaf(sv, s_scalW[p1 * 8 + hf * 4 + j], s_scalB[p1 * 8 + hf * 4 + j]);
                }
            }
            *(f32x4*)(obase + i * 256 + lane * 4) = ov;    // dense 1KB wave store
        }
    } else {
        #pragma unroll
        for (int i = 0; i < 20; i++) {
            int u = lane + 64 * i;
            if (u < 1248) {
                int r2 = u / 39, c = u - 39 * r2;
                float v[8];
                if (c < 8) {
                    u16x8 w = *(const u16x8*)&hbp[r2 * 72 + c * 8];
                    #pragma unroll
                    for (int j = 0; j < 8; j++) v[j] = b2f(w[j]);
                } else {
                    int e = c - 8;
                    int col = EP_P2[e], p1 = EP_P1[e];
                    float sv = ss[r2 * 50 + col];
                    if (EP_KIND[e] == 0) {
                        int idx = (int)(sv + 0.5f);
                        u16x8 w = *(const u16x8*)&s_emb[(p1 + idx) * 8];
                        #pragma unroll
                        for (int j = 0; j < 8; j++) v[j] = b2f(w[j]);
                    } else {
                        #pragma unroll
                        for (int j = 0; j < 8; j++)
                            v[j] = fmaf(sv, s_scalW[p1 * 8 + j], s_scalB[p1 * 8 + j]);
                    }
                }
                u16x8 w;
                #pragma unroll
                for (int j = 0; j < 8; j++) w[j] = f2b(v[j]);
                *(u16x8*)&((u16*)a.out)[(row0 + rbase + r2) * 312 + c * 8] = w;
            }
        }
    }
}

__global__ __launch_bounds__(BLK, 2) void poker_main(
    KArgs a, const u16* __restrict__ arena, const float* __restrict__ biasar)
{
    __shared__ alignas(16) u16   s_w[3 * CHUNK_U16];   // 48KB staging; HB reuse at end
    __shared__ alignas(16) float s_state[4][32 * 50];  // 25.6KB
    __shared__ alignas(16) float s_bias[768];
    __shared__ alignas(16) u16   s_emb[54 * 8];
    __shared__ alignas(16) float s_scalW[48];
    __shared__ alignas(16) float s_scalB[48];

    const int tid = threadIdx.x;
    const int lane = tid & 63, wave = tid >> 6;
    const long row0 = (long)blockIdx.x * 128;
    const bool isf32 = probe_f32(a.p[0]);

    // ---- block-wide staging of tiny tables (covered by the prologue barrier in body)
    {
        const void* srcs[8] = { a.p[1], a.p[2], a.p[21], a.p[22], a.p[23], a.p[24], a.p[25], a.p[26] };
        const int  cnt[8]   = { 5, 14, 7, 12, 2, 5, 7, 2 };
        int base = 0;
        for (int t = 0; t < 8; t++) {
            int n = cnt[t] * 8;
            for (int i = tid; i < n; i += BLK)
                s_emb[base + i] = isf32 ? f2b(((const float*)srcs[t])[i]) : ((const u16*)srcs[t])[i];
            base += n;
        }
        if (tid < 48) {
            s_scalW[tid] = isf32 ? ((const float*)a.p[27])[tid] : b2f(((const u16*)a.p[27])[tid]);
            s_scalB[tid] = isf32 ? ((const float*)a.p[28])[tid] : b2f(((const u16*)a.p[28])[tid]);
        }
        for (int i = tid; i < 192; i += BLK)
            ((f32x4*)s_bias)[i] = ((const f32x4*)biasar)[i];
    }

    float* ss = &s_state[wave][0];
    if (isf32) body<true >(a, arena, s_emb, s_scalW, s_scalB, s_bias, ss, s_w, lane, wave, row0);
    else       body<false>(a, arena, s_emb, s_scalW, s_scalB, s_bias, ss, s_w, lane, wave, row0);
}

extern "C" void kernel_launch(void* const* d_in, const int* in_sizes, int n_in,
                              void* d_out, int out_size, void* d_ws, size_t ws_size,
                              hipStream_t stream) {
    KArgs args;
    for (int i = 0; i < 29; i++) args.p[i] = d_in[i];
    args.out = d_out;
    u16*   arena  = (u16*)d_ws;
    float* biasar = (float*)((char*)d_ws + BIAS_BYTE_OFF);
    int rows = in_sizes[0] / 50;          // 262144
    int blocks = rows / 128;              // 2048

    poker_prep<<<dim3(11), dim3(256), 0, stream>>>(args, arena, biasar);
    poker_main<<<dim3(blocks), dim3(BLK), 0, stream>>>(args, arena, biasar);
}